// Round 1
// baseline (1767.895 us; speedup 1.0000x reference)
//
#include <hip/hip_runtime.h>

typedef _Float16 f16;
typedef _Float16 f16x8 __attribute__((ext_vector_type(8)));
typedef float f32x4 __attribute__((ext_vector_type(4)));

#define N_ROWS 500000
#define EPS_LOG 1e-7f
#define EPS_LN  1e-5f

__device__ __forceinline__ void gload_lds16(const f16* g, f16* l) {
  __builtin_amdgcn_global_load_lds(
      (const __attribute__((address_space(1))) void*)g,
      (__attribute__((address_space(3))) void*)l, 16, 0, 0);
}

// ---------------- prep: f32 weights -> f16, slab-permuted, in ws ----------------
// ws (f16 elements):
//   [0, 16384)            : W1 padded to K=64: idx = ((kt*4+kgrp)*256 + j)*8 + e, kt<2
//   [16384 + li*65536 ...): W_{li+2}:          idx = ((kt*4+kgrp)*256 + j)*8 + e, kt<8
// where k = kt*32 + kgrp*8 + e and the value is W[j][k] (B-fragment order).
__global__ void prep_kernel(const float* __restrict__ W1,
                            const float* __restrict__ W2, const float* __restrict__ W3,
                            const float* __restrict__ W4, const float* __restrict__ W5,
                            const float* __restrict__ W6, const float* __restrict__ W7,
                            f16* __restrict__ ws) {
  int idx = blockIdx.x * 256 + threadIdx.x;
  if (idx < 16384) {
    int e = idx & 7, j = (idx >> 3) & 255, kgrp = (idx >> 11) & 3, kt = idx >> 13;
    int k = kt * 32 + kgrp * 8 + e;
    float v = (k < 39) ? W1[j * 39 + k] : 0.0f;
    ws[idx] = (f16)v;
  } else {
    int o = idx - 16384;
    int li = o >> 16;
    o &= 65535;
    const float* W = (li == 0) ? W2 : (li == 1) ? W3 : (li == 2) ? W4
                   : (li == 3) ? W5 : (li == 4) ? W6 : W7;
    int e = o & 7, j = (o >> 3) & 255, kgrp = (o >> 11) & 3, kt = o >> 13;
    int k = kt * 32 + kgrp * 8 + e;
    ws[idx] = (f16)W[j * 256 + k];
  }
}

// ---------------- fused MLP kernel ----------------
// Block: 256 threads = 4 waves; 64 rows/block, 16 rows per wave (one 16x16 M-tile).
// h kept in LDS as f16 (XOR-swizzled). Weights staged per-32-K slab into LDS.
__global__ __launch_bounds__(256, 2)
void mlp_kernel(const float* __restrict__ x, const f16* __restrict__ wsw,
                const float* __restrict__ b1, const float* __restrict__ b2,
                const float* __restrict__ b3, const float* __restrict__ b4,
                const float* __restrict__ b5, const float* __restrict__ b6,
                const float* __restrict__ b7, const float* __restrict__ W8,
                const float* __restrict__ b8, const float* __restrict__ gamma,
                const float* __restrict__ beta, float* __restrict__ out) {
  __shared__ __attribute__((aligned(16))) f16 hbuf[64 * 256];   // 32 KB
  __shared__ __attribute__((aligned(16))) f16 wslab[8192];      // 16 KB
  __shared__ float rowstats[64 * 2];                            // mu, inv_std

  const int t = threadIdx.x;
  const int lane = t & 63;
  const int wid = t >> 6;       // wave 0..3
  const int lm = lane & 15;     // lane % 16
  const int lg = lane >> 4;     // lane / 16
  const long rowbase = (long)blockIdx.x * 64;

  // ---- input fill: t = 0.1*log(x+eps) as f16 into [64][64] (K padded to 64) ----
  #pragma unroll
  for (int m = 0; m < 16; ++m) {
    int e = m * 256 + t;
    int r = e >> 6, k = e & 63;
    long gr = rowbase + r;
    float tv = 0.0f;
    if (k < 39) {
      float xv = (gr < N_ROWS) ? x[gr * 39 + k] : 1.0f;
      tv = 0.1f * __logf(xv + EPS_LOG);
    }
    int s = (r >> 1) & 7;
    hbuf[r * 64 + (k ^ (s << 3))] = (f16)tv;
  }
  __syncthreads();

  const int myrow = wid * 16 + lm;          // A-fragment row this lane serves
  const int sA = ((myrow >> 1) & 7) << 3;   // element-index XOR swizzle

  f32x4 acc[16];

  // epilogue: bias + activation + f16 store to hbuf + LN stats for next layer.
  // Lane holds acc[nt][i] for row wid*16 + lg*4 + i, col nt*16 + lm.
  auto epilogue = [&](const float* bias, bool is_tanh) {
    float sm0 = 0, sm1 = 0, sm2 = 0, sm3 = 0;
    float sq0 = 0, sq1 = 0, sq2 = 0, sq3 = 0;
    #pragma unroll
    for (int nt = 0; nt < 16; ++nt) {
      float bv = bias[nt * 16 + lm];
      #pragma unroll
      for (int i = 0; i < 4; ++i) {
        float v = acc[nt][i] + bv;
        float a;
        if (is_tanh) {
          float e2 = __expf(2.0f * v);
          a = 1.0f - 2.0f / (e2 + 1.0f);
        } else {
          a = (v > 0.0f) ? v : (__expf(v) - 1.0f);
        }
        int r = wid * 16 + lg * 4 + i;
        int s = (r >> 1) & 7;
        hbuf[r * 256 + ((nt * 16 + lm) ^ (s << 3))] = (f16)a;
        float aa = a * a;
        if (i == 0) { sm0 += a; sq0 += aa; }
        else if (i == 1) { sm1 += a; sq1 += aa; }
        else if (i == 2) { sm2 += a; sq2 += aa; }
        else { sm3 += a; sq3 += aa; }
      }
    }
    #pragma unroll
    for (int off = 1; off < 16; off <<= 1) {
      sm0 += __shfl_xor(sm0, off, 64); sq0 += __shfl_xor(sq0, off, 64);
      sm1 += __shfl_xor(sm1, off, 64); sq1 += __shfl_xor(sq1, off, 64);
      sm2 += __shfl_xor(sm2, off, 64); sq2 += __shfl_xor(sq2, off, 64);
      sm3 += __shfl_xor(sm3, off, 64); sq3 += __shfl_xor(sq3, off, 64);
    }
    if (lm < 4) {
      float sm = (lm == 0) ? sm0 : (lm == 1) ? sm1 : (lm == 2) ? sm2 : sm3;
      float sq = (lm == 0) ? sq0 : (lm == 1) ? sq1 : (lm == 2) ? sq2 : sq3;
      float mu = sm * (1.0f / 256.0f);
      float var = sq * (1.0f / 256.0f) - mu * mu;
      float is = rsqrtf(var + EPS_LN);
      int r = wid * 16 + lg * 4 + lm;
      rowstats[r * 2] = mu;
      rowstats[r * 2 + 1] = is;
    }
  };

  // ================= layer 1: tanh(t @ W1^T + b1), K=64 =================
  {
    f16x8 a1[2];
    #pragma unroll
    for (int kt = 0; kt < 2; ++kt) {
      int c = kt * 32 + lg * 8;
      a1[kt] = *(const f16x8*)&hbuf[myrow * 64 + (c ^ sA)];
    }
    #pragma unroll
    for (int i = 0; i < 16; ++i) acc[i] = (f32x4){0.f, 0.f, 0.f, 0.f};
    #pragma unroll
    for (int kt = 0; kt < 2; ++kt) {
      __syncthreads();                       // slab free (all waves done reading)
      #pragma unroll
      for (int m = 0; m < 4; ++m) {
        int d = m * 256 + t;
        gload_lds16(wsw + kt * 8192 + d * 8, &wslab[d * 8]);
      }
      __syncthreads();                       // data ready (drains vmcnt)
      #pragma unroll
      for (int nt = 0; nt < 16; ++nt) {
        f16x8 bf = *(const f16x8*)&wslab[lg * 2048 + (nt * 16 + lm) * 8];
        acc[nt] = __builtin_amdgcn_mfma_f32_16x16x32_f16(a1[kt], bf, acc[nt], 0, 0, 0);
      }
    }
    epilogue(b1, true);
  }

  // ================= layers 2..7: elu(LN(h) @ W^T + b) =================
  auto lnlayer = [&](const f16* Wl, const float* bias) {
    float mu = rowstats[myrow * 2];
    float is = rowstats[myrow * 2 + 1];
    f16x8 a[8];
    #pragma unroll
    for (int kt = 0; kt < 8; ++kt) {
      int c = kt * 32 + lg * 8;
      f16x8 hv = *(const f16x8*)&hbuf[myrow * 256 + (c ^ sA)];
      f32x4 g0 = *(const f32x4*)&gamma[c];
      f32x4 g1 = *(const f32x4*)&gamma[c + 4];
      f32x4 be0 = *(const f32x4*)&beta[c];
      f32x4 be1 = *(const f32x4*)&beta[c + 4];
      f16x8 z;
      #pragma unroll
      for (int e = 0; e < 8; ++e) {
        float gv = (e < 4) ? g0[e & 3] : g1[e & 3];
        float bv = (e < 4) ? be0[e & 3] : be1[e & 3];
        float h = (float)hv[e];
        float cg = is * gv;
        z[e] = (f16)(h * cg + (bv - mu * cg));
      }
      a[kt] = z;
    }
    #pragma unroll
    for (int i = 0; i < 16; ++i) acc[i] = (f32x4){0.f, 0.f, 0.f, 0.f};
    #pragma unroll
    for (int kt = 0; kt < 8; ++kt) {
      __syncthreads();
      #pragma unroll
      for (int m = 0; m < 4; ++m) {
        int d = m * 256 + t;
        gload_lds16(Wl + kt * 8192 + d * 8, &wslab[d * 8]);
      }
      __syncthreads();
      #pragma unroll
      for (int nt = 0; nt < 16; ++nt) {
        f16x8 bf = *(const f16x8*)&wslab[lg * 2048 + (nt * 16 + lm) * 8];
        acc[nt] = __builtin_amdgcn_mfma_f32_16x16x32_f16(a[kt], bf, acc[nt], 0, 0, 0);
      }
    }
    epilogue(bias, false);
  };

  #pragma unroll 1
  for (int li = 0; li < 6; ++li) {
    const f16* Wl = wsw + 16384 + li * 65536;
    const float* bias = (li == 0) ? b2 : (li == 1) ? b3 : (li == 2) ? b4
                      : (li == 3) ? b5 : (li == 4) ? b6 : b7;
    lnlayer(Wl, bias);
  }

  // ================= layer 8: LN(h) @ W8^T + b8 (vector dot) =================
  {
    float mu = rowstats[myrow * 2];
    float is = rowstats[myrow * 2 + 1];
    float d = 0.0f;
    #pragma unroll
    for (int kt = 0; kt < 8; ++kt) {
      int c = kt * 32 + lg * 8;
      f16x8 hv = *(const f16x8*)&hbuf[myrow * 256 + (c ^ sA)];
      f32x4 g0 = *(const f32x4*)&gamma[c];
      f32x4 g1 = *(const f32x4*)&gamma[c + 4];
      f32x4 be0 = *(const f32x4*)&beta[c];
      f32x4 be1 = *(const f32x4*)&beta[c + 4];
      f32x4 w0 = *(const f32x4*)&W8[c];
      f32x4 w1 = *(const f32x4*)&W8[c + 4];
      #pragma unroll
      for (int e = 0; e < 8; ++e) {
        float gv = (e < 4) ? g0[e & 3] : g1[e & 3];
        float bv = (e < 4) ? be0[e & 3] : be1[e & 3];
        float wv = (e < 4) ? w0[e & 3] : w1[e & 3];
        float h = (float)hv[e];
        float cg = is * gv;
        float z = h * cg + (bv - mu * cg);
        d += z * wv;
      }
    }
    d += __shfl_xor(d, 16, 64);
    d += __shfl_xor(d, 32, 64);
    if (lg == 0) {
      long gr = rowbase + myrow;
      if (gr < N_ROWS) out[gr] = d + b8[0];
    }
  }
}

extern "C" void kernel_launch(void* const* d_in, const int* in_sizes, int n_in,
                              void* d_out, int out_size, void* d_ws, size_t ws_size,
                              hipStream_t stream) {
  const float* x  = (const float*)d_in[0];
  const float* W1 = (const float*)d_in[1];
  const float* b1 = (const float*)d_in[2];
  const float* W2 = (const float*)d_in[3];
  const float* b2 = (const float*)d_in[4];
  const float* W3 = (const float*)d_in[5];
  const float* b3 = (const float*)d_in[6];
  const float* W4 = (const float*)d_in[7];
  const float* b4 = (const float*)d_in[8];
  const float* W5 = (const float*)d_in[9];
  const float* b5 = (const float*)d_in[10];
  const float* W6 = (const float*)d_in[11];
  const float* b6 = (const float*)d_in[12];
  const float* W7 = (const float*)d_in[13];
  const float* b7 = (const float*)d_in[14];
  const float* W8 = (const float*)d_in[15];
  const float* b8 = (const float*)d_in[16];
  const float* gm = (const float*)d_in[17];
  const float* bt = (const float*)d_in[18];
  f16* ws = (f16*)d_ws;
  float* out = (float*)d_out;

  // convert + permute weights into ws (819200 bytes needed)
  prep_kernel<<<1600, 256, 0, stream>>>(W1, W2, W3, W4, W5, W6, W7, ws);

  int nblk = (N_ROWS + 63) / 64;   // 7813
  mlp_kernel<<<nblk, 256, 0, stream>>>(x, ws, b1, b2, b3, b4, b5, b6, b7,
                                       W8, b8, gm, bt, out);
}

// Round 5
// 1646.926 us; speedup vs baseline: 1.0735x; 1.0735x over previous
//
#include <hip/hip_runtime.h>

typedef _Float16 f16;
typedef _Float16 f16x8 __attribute__((ext_vector_type(8)));
typedef float f32x4 __attribute__((ext_vector_type(4)));

#define N_ROWS 500000
#define EPS_LOG 1e-7f
#define EPS_LN  1e-5f

// ws layout (EXACTLY 819200 bytes, footprint proven safe in round 1):
//   f16 idx [0, 10240)      : W1p [256][40], W1p[j][k]=W1[j][k] (k<39), k=39 -> 0
//   bytes [20480, 32768)    : f32 sg[6][256] (unused), bb[6][256] = beta@W^T + b
//   f16 idx [16384, 409600) : Wg layers 2..7, plain [256][256], Wg[j][k]=W[j][k]*gamma[k]
#define CST_BYTE_OFF 20480

// ---------------- prep ----------------
__global__ void prep_kernel(const float* __restrict__ W1,
                            const float* __restrict__ W2, const float* __restrict__ W3,
                            const float* __restrict__ W4, const float* __restrict__ W5,
                            const float* __restrict__ W6, const float* __restrict__ W7,
                            const float* __restrict__ b2, const float* __restrict__ b3,
                            const float* __restrict__ b4, const float* __restrict__ b5,
                            const float* __restrict__ b6, const float* __restrict__ b7,
                            const float* __restrict__ gamma, const float* __restrict__ beta,
                            f16* __restrict__ ws) {
  float* cstF = (float*)((char*)ws + CST_BYTE_OFF);
  int idx = blockIdx.x * 256 + threadIdx.x;
  if (idx < 10240) {            // W1p [256][40]
    int j = idx / 40, k = idx - j * 40;
    ws[idx] = (f16)((k < 39) ? W1[j * 39 + k] : 0.0f);
  } else if (idx < 16384) {
    // cst region lives here (bytes [20480,32768)) — written below
  } else if (idx < 409600) {    // Wg = W * gamma, plain row-major
    int o = idx - 16384;
    int li = o >> 16;  o &= 65535;
    const float* W = (li == 0) ? W2 : (li == 1) ? W3 : (li == 2) ? W4
                   : (li == 3) ? W5 : (li == 4) ? W6 : W7;
    int j = o >> 8, k = o & 255;
    ws[idx] = (f16)(W[j * 256 + k] * gamma[k]);
  } else if (idx < 411136) {    // sg[li][j] (kept, unused) ; bb[li][j] = beta@W^T + b
    int o = idx - 409600;
    int li = o >> 8, j = o & 255;
    const float* W = (li == 0) ? W2 : (li == 1) ? W3 : (li == 2) ? W4
                   : (li == 3) ? W5 : (li == 4) ? W6 : W7;
    const float* b = (li == 0) ? b2 : (li == 1) ? b3 : (li == 2) ? b4
                   : (li == 3) ? b5 : (li == 4) ? b6 : b7;
    float sg = 0.f, bb = 0.f;
    for (int k = 0; k < 256; ++k) {
      float w = W[j * 256 + k];
      sg += w * gamma[k];
      bb += w * beta[k];
    }
    cstF[li * 256 + j] = sg;
    cstF[1536 + li * 256 + j] = bb + b[j];
  }
}

// ---------------- fused MLP: barrier-free, z-normalized activations in LDS ----------
// 256 threads = 4 waves; 128 rows/block; wave owns rows [wid*32, wid*32+32).
// ALL hbuf traffic is at row-stride 256 within the wave's own band (the round-2..4
// bug was the input at stride 64 overlapping other waves' stride-256 epilogue).
// hbuf stores z = (h-mu)*is (normalized); layers consume v = z@Wg^T + bb.
__global__ __launch_bounds__(256, 2)
void mlp_kernel(const float* __restrict__ x, const f16* __restrict__ wsw,
                const float* __restrict__ b1, const float* __restrict__ W8,
                const float* __restrict__ b8, const float* __restrict__ gamma,
                const float* __restrict__ beta, float* __restrict__ out) {
  __shared__ __attribute__((aligned(16))) f16 hbuf[128 * 256];   // 64 KB

  const float* cstF = (const float*)((const char*)wsw + CST_BYTE_OFF);
  const int t = threadIdx.x;
  const int lane = t & 63;
  const int wid = t >> 6;
  const int lm = lane & 15;
  const int lg = lane >> 4;
  const long rowbase = (long)blockIdx.x * 128;
  const int R0 = wid * 32;                 // wave's row band [R0, R0+32)
  const int myrow0 = R0 + lm;              // A-frag row, tile 0
  const int myrow1 = R0 + 16 + lm;         // A-frag row, tile 1
  const int sA0 = ((myrow0 >> 1) & 7) << 3;
  const int sA1 = ((myrow1 >> 1) & 7) << 3;

  // ---- input fill (wave-private, STRIDE 256, cols 0..63 swizzled) ----
  #pragma unroll 1
  for (int i = 0; i < 32; ++i) {
    int r = R0 + i;
    long gr = rowbase + r;
    float tv = 0.0f;
    if (lane < 39) {
      float xv = (gr < N_ROWS) ? x[gr * 39 + lane] : 1.0f;
      tv = 0.1f * __logf(xv + EPS_LOG);
    }
    hbuf[r * 256 + (lane ^ (((r >> 1) & 7) << 3))] = (f16)tv;
  }

  f32x4 acc0[16], acc1[16];

  // epilogue for one 16-row tile: v = acc + cvec[col]; a = act(v); row stats;
  // store z = (a - mu)*is to hbuf. Lane (lg,lm): acc[nt][i] = row rbase+lg*4+i,
  // col nt*16+lm (MFMA C layout m89). Stats reduce over the 16-lane lg-group.
  auto do_tile = [&](f32x4* acc, int rbase, bool tanh_act, const float* cvec) {
    float nm[4] = {0, 0, 0, 0}, nq[4] = {0, 0, 0, 0};
    #pragma unroll
    for (int nt = 0; nt < 16; ++nt) {
      float c0 = cvec[nt * 16 + lm];
      #pragma unroll
      for (int i = 0; i < 4; ++i) {
        float v = acc[nt][i] + c0;
        float a;
        if (tanh_act) {
          float e2 = __expf(2.f * v);
          a = 1.f - 2.f / (e2 + 1.f);
        } else {
          a = (v > 0.f) ? v : (__expf(v) - 1.f);
        }
        acc[nt][i] = a;            // keep activation for the z-store pass
        nm[i] += a;
        nq[i] = fmaf(a, a, nq[i]);
      }
    }
    #pragma unroll
    for (int off = 1; off < 16; off <<= 1) {
      #pragma unroll
      for (int i = 0; i < 4; ++i) {
        nm[i] += __shfl_xor(nm[i], off, 64);
        nq[i] += __shfl_xor(nq[i], off, 64);
      }
    }
    float mu[4], is_[4];
    #pragma unroll
    for (int i = 0; i < 4; ++i) {
      float m = nm[i] * (1.f / 256.f);
      float var = nq[i] * (1.f / 256.f) - m * m;
      mu[i] = m;
      is_[i] = rsqrtf(var + EPS_LN);
    }
    #pragma unroll
    for (int nt = 0; nt < 16; ++nt) {
      int col = nt * 16 + lm;
      #pragma unroll
      for (int i = 0; i < 4; ++i) {
        int r = rbase + lg * 4 + i;
        hbuf[r * 256 + (col ^ (((r >> 1) & 7) << 3))] =
            (f16)((acc[nt][i] - mu[i]) * is_[i]);
      }
    }
  };

  // ================= layer 1: z1 = LN-normalize(tanh(t @ W1^T + b1)) =================
  {
    #pragma unroll
    for (int i = 0; i < 16; ++i) { acc0[i] = (f32x4){0,0,0,0}; acc1[i] = (f32x4){0,0,0,0}; }
    #pragma unroll
    for (int kt = 0; kt < 2; ++kt) {
      f16x8 av0 = *(const f16x8*)&hbuf[myrow0 * 256 + ((kt * 32 + lg * 8) ^ sA0)];
      f16x8 av1 = *(const f16x8*)&hbuf[myrow1 * 256 + ((kt * 32 + lg * 8) ^ sA1)];
      #pragma unroll
      for (int nt = 0; nt < 16; ++nt) {
        int j40 = (nt * 16 + lm) * 40;
        f16x8 bf = 0;
        if (kt == 0)       bf = *(const f16x8*)&wsw[j40 + lg * 8];
        else if (lg == 0)  bf = *(const f16x8*)&wsw[j40 + 32];
        acc0[nt] = __builtin_amdgcn_mfma_f32_16x16x32_f16(av0, bf, acc0[nt], 0, 0, 0);
        acc1[nt] = __builtin_amdgcn_mfma_f32_16x16x32_f16(av1, bf, acc1[nt], 0, 0, 0);
      }
    }
    do_tile(acc0, R0,      true, b1);
    do_tile(acc1, R0 + 16, true, b1);
  }

  // ================= layers 2..7: z = LN-normalize(elu(z @ Wg^T + bb)) =================
  #pragma unroll 1
  for (int li = 0; li < 6; ++li) {
    const f16* wbase = wsw + 16384 + li * 65536 + lm * 256 + lg * 8;  // + nt*4096 + kt*32
    #pragma unroll
    for (int i = 0; i < 16; ++i) { acc0[i] = (f32x4){0,0,0,0}; acc1[i] = (f32x4){0,0,0,0}; }
    #pragma unroll 1
    for (int kt = 0; kt < 8; ++kt) {
      f16x8 av0 = *(const f16x8*)&hbuf[myrow0 * 256 + ((kt * 32 + lg * 8) ^ sA0)];
      f16x8 av1 = *(const f16x8*)&hbuf[myrow1 * 256 + ((kt * 32 + lg * 8) ^ sA1)];
      #pragma unroll
      for (int nt = 0; nt < 16; ++nt) {
        f16x8 bf = *(const f16x8*)&wbase[nt * 4096 + kt * 32];
        acc0[nt] = __builtin_amdgcn_mfma_f32_16x16x32_f16(av0, bf, acc0[nt], 0, 0, 0);
        acc1[nt] = __builtin_amdgcn_mfma_f32_16x16x32_f16(av1, bf, acc1[nt], 0, 0, 0);
      }
    }
    do_tile(acc0, R0,      false, cstF + 1536 + li * 256);
    do_tile(acc1, R0 + 16, false, cstF + 1536 + li * 256);
  }

  // ================= layer 8: out = z7 . (W8*gamma) + (beta@W8 + b8) =================
  {
    float wg8[16], be8 = 0.f;
    #pragma unroll
    for (int j = 0; j < 16; ++j) {
      int c = lm * 16 + j;
      float w = W8[c];
      wg8[j] = w * gamma[c];
      be8 = fmaf(w, beta[c], be8);
    }
    #pragma unroll
    for (int off = 1; off < 16; off <<= 1) be8 += __shfl_xor(be8, off, 64);
    float cb8 = be8 + b8[0];
    #pragma unroll
    for (int tile = 0; tile < 2; ++tile) {
      #pragma unroll
      for (int i = 0; i < 4; ++i) {
        int r = R0 + tile * 16 + lg * 4 + i;
        int s3 = ((r >> 1) & 7) << 3;
        f16x8 h0 = *(const f16x8*)&hbuf[r * 256 + ((lm * 16) ^ s3)];
        f16x8 h1 = *(const f16x8*)&hbuf[r * 256 + ((lm * 16 + 8) ^ s3)];
        float d = 0.f;
        #pragma unroll
        for (int j = 0; j < 8; ++j) d = fmaf((float)h0[j], wg8[j], d);
        #pragma unroll
        for (int j = 0; j < 8; ++j) d = fmaf((float)h1[j], wg8[8 + j], d);
        #pragma unroll
        for (int off = 1; off < 16; off <<= 1) d += __shfl_xor(d, off, 64);
        if (lm == 0) {
          long gr = rowbase + r;
          if (gr < N_ROWS) out[gr] = d + cb8;
        }
      }
    }
  }
}

extern "C" void kernel_launch(void* const* d_in, const int* in_sizes, int n_in,
                              void* d_out, int out_size, void* d_ws, size_t ws_size,
                              hipStream_t stream) {
  const float* x  = (const float*)d_in[0];
  const float* W1 = (const float*)d_in[1];
  const float* b1 = (const float*)d_in[2];
  const float* W2 = (const float*)d_in[3];
  const float* b2 = (const float*)d_in[4];
  const float* W3 = (const float*)d_in[5];
  const float* b3 = (const float*)d_in[6];
  const float* W4 = (const float*)d_in[7];
  const float* b4 = (const float*)d_in[8];
  const float* W5 = (const float*)d_in[9];
  const float* b5 = (const float*)d_in[10];
  const float* W6 = (const float*)d_in[11];
  const float* b6 = (const float*)d_in[12];
  const float* W7 = (const float*)d_in[13];
  const float* b7 = (const float*)d_in[14];
  const float* W8 = (const float*)d_in[15];
  const float* b8 = (const float*)d_in[16];
  const float* gm = (const float*)d_in[17];
  const float* bt = (const float*)d_in[18];
  f16* ws = (f16*)d_ws;
  float* out = (float*)d_out;

  prep_kernel<<<1606, 256, 0, stream>>>(W1, W2, W3, W4, W5, W6, W7,
                                        b2, b3, b4, b5, b6, b7, gm, bt, ws);

  int nblk = (N_ROWS + 127) / 128;   // 3907
  mlp_kernel<<<nblk, 256, 0, stream>>>(x, ws, b1, W8, b8, gm, bt, out);
}

// Round 7
// 1033.904 us; speedup vs baseline: 1.7099x; 1.5929x over previous
//
#include <hip/hip_runtime.h>

typedef _Float16 f16;
typedef _Float16 f16x8 __attribute__((ext_vector_type(8)));
typedef float f32x4 __attribute__((ext_vector_type(4)));

#define N_ROWS 500000
#define EPS_LOG 1e-7f
#define EPS_LN  1e-5f

// ws layout (EXACTLY 819200 bytes, footprint proven safe):
//   f16 idx [0, 10240)      : W1p [256][40], W1p[j][k]=W1[j][k] (k<39), k=39 -> 0
//   bytes [20480, 32768)    : f32 sg[6][256] (unused), bb[6][256] = beta@W^T + b
//   f16 idx [16384, 409600) : Wg layers 2..7 SLAB-PERMUTED:
//       idx = 16384 + li*65536 + kt*8192 + kgrp*2048 + j*8 + e
//       value = W[j][k]*gamma[k],  k = kt*32 + kgrp*8 + e
#define CST_BYTE_OFF 20480

// ---------------- prep ----------------
__global__ void prep_kernel(const float* __restrict__ W1,
                            const float* __restrict__ W2, const float* __restrict__ W3,
                            const float* __restrict__ W4, const float* __restrict__ W5,
                            const float* __restrict__ W6, const float* __restrict__ W7,
                            const float* __restrict__ b2, const float* __restrict__ b3,
                            const float* __restrict__ b4, const float* __restrict__ b5,
                            const float* __restrict__ b6, const float* __restrict__ b7,
                            const float* __restrict__ gamma, const float* __restrict__ beta,
                            f16* __restrict__ ws) {
  float* cstF = (float*)((char*)ws + CST_BYTE_OFF);
  int idx = blockIdx.x * 256 + threadIdx.x;
  if (idx < 10240) {            // W1p [256][40]
    int j = idx / 40, k = idx - j * 40;
    ws[idx] = (f16)((k < 39) ? W1[j * 39 + k] : 0.0f);
  } else if (idx < 16384) {
    // cst region lives at bytes [20480,32768) — written below
  } else if (idx < 409600) {    // Wg = W*gamma, slab-permuted for LDS staging
    int o = idx - 16384;
    int li = o >> 16;  o &= 65535;
    const float* W = (li == 0) ? W2 : (li == 1) ? W3 : (li == 2) ? W4
                   : (li == 3) ? W5 : (li == 4) ? W6 : W7;
    int e = o & 7, j = (o >> 3) & 255, kgrp = (o >> 11) & 3, kt = o >> 13;
    int k = kt * 32 + kgrp * 8 + e;
    ws[idx] = (f16)(W[j * 256 + k] * gamma[k]);
  } else if (idx < 411136) {    // sg (unused) ; bb[li][j] = beta@W^T + b
    int o = idx - 409600;
    int li = o >> 8, j = o & 255;
    const float* W = (li == 0) ? W2 : (li == 1) ? W3 : (li == 2) ? W4
                   : (li == 3) ? W5 : (li == 4) ? W6 : W7;
    const float* b = (li == 0) ? b2 : (li == 1) ? b3 : (li == 2) ? b4
                   : (li == 3) ? b5 : (li == 4) ? b6 : b7;
    float sg = 0.f, bb = 0.f;
    for (int k = 0; k < 256; ++k) {
      float w = W[j * 256 + k];
      sg += w * gamma[k];
      bb += w * beta[k];
    }
    cstF[li * 256 + j] = sg;
    cstF[1536 + li * 256 + j] = bb + b[j];
  }
}

// ---------------- fused MLP: reg-staged weight slabs, wave-private activations ------
// 256 threads = 4 waves; 128 rows/block; wave owns rows [wid*32, wid*32+32).
// ALL hbuf traffic is wave-private at row-stride 256 (r5-proven).
// Weight slab (16 KB = one K-step) staged global->VGPR->ds_write_b128 (NO
// global_load_lds: r6 isolated a miscompile/race in that builtin across barriers).
// T14 split: loads for kt+1 issued before kt's compute; ds_write at top of kt+1.
// Sync: 2x __syncthreads per step — standard ds_write visibility, bulletproof.
__global__ __launch_bounds__(256, 2)
void mlp_kernel(const float* __restrict__ x, const f16* __restrict__ wsw,
                const float* __restrict__ b1, const float* __restrict__ W8,
                const float* __restrict__ b8, const float* __restrict__ gamma,
                const float* __restrict__ beta, float* __restrict__ out) {
  __shared__ __attribute__((aligned(16))) f16 hbuf[128 * 256];   // 64 KB
  __shared__ __attribute__((aligned(16))) f16 wslab[8192];       // 16 KB

  const float* cstF = (const float*)((const char*)wsw + CST_BYTE_OFF);
  const int t = threadIdx.x;
  const int lane = t & 63;
  const int wid = t >> 6;
  const int lm = lane & 15;
  const int lg = lane >> 4;
  const long rowbase = (long)blockIdx.x * 128;
  const int R0 = wid * 32;                 // wave's row band [R0, R0+32)
  const int myrow0 = R0 + lm;              // A-frag row, tile 0
  const int myrow1 = R0 + 16 + lm;         // A-frag row, tile 1
  const int sA0 = ((myrow0 >> 1) & 7) << 3;
  const int sA1 = ((myrow1 >> 1) & 7) << 3;

  // in-flight slab chunks (named regs, rule #20: no runtime-indexed arrays)
  f16x8 ld0, ld1, ld2, ld3;
  auto slab_load = [&](const f16* g) {     // issue 4x global_load_dwordx4 -> regs
    ld0 = *(const f16x8*)(g + (0 * 256 + t) * 8);
    ld1 = *(const f16x8*)(g + (1 * 256 + t) * 8);
    ld2 = *(const f16x8*)(g + (2 * 256 + t) * 8);
    ld3 = *(const f16x8*)(g + (3 * 256 + t) * 8);
  };
  auto slab_write = [&]() {                // regs -> wslab via ds_write_b128
    *(f16x8*)&wslab[(0 * 256 + t) * 8] = ld0;
    *(f16x8*)&wslab[(1 * 256 + t) * 8] = ld1;
    *(f16x8*)&wslab[(2 * 256 + t) * 8] = ld2;
    *(f16x8*)&wslab[(3 * 256 + t) * 8] = ld3;
  };

  const f16* WgBase = wsw + 16384;
  slab_load(WgBase);                       // slab (li=2-layer, kt=0) in flight

  // ---- input fill (wave-private, STRIDE 256, cols 0..63 swizzled) ----
  #pragma unroll 1
  for (int i = 0; i < 32; ++i) {
    int r = R0 + i;
    long gr = rowbase + r;
    float tv = 0.0f;
    if (lane < 39) {
      float xv = (gr < N_ROWS) ? x[gr * 39 + lane] : 1.0f;
      tv = 0.1f * __logf(xv + EPS_LOG);
    }
    hbuf[r * 256 + (lane ^ (((r >> 1) & 7) << 3))] = (f16)tv;
  }

  f32x4 acc0[16], acc1[16];

  // epilogue for one 16-row tile: v = acc + cvec[col]; a = act(v); row stats;
  // store z = (a - mu)*is to hbuf (wave-private rows). MFMA C layout (m89):
  // lane (lg,lm) holds acc[nt][i] = row rbase+lg*4+i, col nt*16+lm.
  auto do_tile = [&](f32x4* acc, int rbase, bool tanh_act, const float* cvec) {
    float nm[4] = {0, 0, 0, 0}, nq[4] = {0, 0, 0, 0};
    #pragma unroll
    for (int nt = 0; nt < 16; ++nt) {
      float c0 = cvec[nt * 16 + lm];
      #pragma unroll
      for (int i = 0; i < 4; ++i) {
        float v = acc[nt][i] + c0;
        float a;
        if (tanh_act) {
          float e2 = __expf(2.f * v);
          a = 1.f - 2.f / (e2 + 1.f);
        } else {
          a = (v > 0.f) ? v : (__expf(v) - 1.f);
        }
        acc[nt][i] = a;
        nm[i] += a;
        nq[i] = fmaf(a, a, nq[i]);
      }
    }
    #pragma unroll
    for (int off = 1; off < 16; off <<= 1) {
      #pragma unroll
      for (int i = 0; i < 4; ++i) {
        nm[i] += __shfl_xor(nm[i], off, 64);
        nq[i] += __shfl_xor(nq[i], off, 64);
      }
    }
    float mu[4], is_[4];
    #pragma unroll
    for (int i = 0; i < 4; ++i) {
      float m = nm[i] * (1.f / 256.f);
      float var = nq[i] * (1.f / 256.f) - m * m;
      mu[i] = m;
      is_[i] = rsqrtf(var + EPS_LN);
    }
    #pragma unroll
    for (int nt = 0; nt < 16; ++nt) {
      int col = nt * 16 + lm;
      #pragma unroll
      for (int i = 0; i < 4; ++i) {
        int r = rbase + lg * 4 + i;
        hbuf[r * 256 + (col ^ (((r >> 1) & 7) << 3))] =
            (f16)((acc[nt][i] - mu[i]) * is_[i]);
      }
    }
  };

  // ================= layer 1: z1 = LN-normalize(tanh(t @ W1^T + b1)) =================
  // B direct from global (tiny, one-time, r5-proven); slab(2,0) loads in flight.
  {
    #pragma unroll
    for (int i = 0; i < 16; ++i) { acc0[i] = (f32x4){0,0,0,0}; acc1[i] = (f32x4){0,0,0,0}; }
    #pragma unroll
    for (int kt = 0; kt < 2; ++kt) {
      f16x8 av0 = *(const f16x8*)&hbuf[myrow0 * 256 + ((kt * 32 + lg * 8) ^ sA0)];
      f16x8 av1 = *(const f16x8*)&hbuf[myrow1 * 256 + ((kt * 32 + lg * 8) ^ sA1)];
      #pragma unroll
      for (int nt = 0; nt < 16; ++nt) {
        int j40 = (nt * 16 + lm) * 40;
        f16x8 bf = 0;
        if (kt == 0)       bf = *(const f16x8*)&wsw[j40 + lg * 8];
        else if (lg == 0)  bf = *(const f16x8*)&wsw[j40 + 32];
        acc0[nt] = __builtin_amdgcn_mfma_f32_16x16x32_f16(av0, bf, acc0[nt], 0, 0, 0);
        acc1[nt] = __builtin_amdgcn_mfma_f32_16x16x32_f16(av1, bf, acc1[nt], 0, 0, 0);
      }
    }
    do_tile(acc0, R0,      true, b1);
    do_tile(acc1, R0 + 16, true, b1);
  }

  // ================= layers 2..7: z = LN-normalize(elu(z @ Wg^T + bb)) =================
  #pragma unroll 1
  for (int li = 0; li < 6; ++li) {
    #pragma unroll
    for (int i = 0; i < 16; ++i) { acc0[i] = (f32x4){0,0,0,0}; acc1[i] = (f32x4){0,0,0,0}; }
    #pragma unroll 1
    for (int kt = 0; kt < 8; ++kt) {
      // regs hold slab (li,kt); wslab free since previous FREE barrier
      slab_write();
      if (kt < 7)       slab_load(WgBase + li * 65536 + (kt + 1) * 8192);
      else if (li < 5)  slab_load(WgBase + (li + 1) * 65536);
      __syncthreads();   // READY: all waves' ds_writes visible (lgkmcnt drained)
      {
        f16x8 av0 = *(const f16x8*)&hbuf[myrow0 * 256 + ((kt * 32 + lg * 8) ^ sA0)];
        f16x8 av1 = *(const f16x8*)&hbuf[myrow1 * 256 + ((kt * 32 + lg * 8) ^ sA1)];
        #pragma unroll
        for (int nt = 0; nt < 16; ++nt) {
          f16x8 bf = *(const f16x8*)&wslab[lg * 2048 + (nt * 16 + lm) * 8];
          acc0[nt] = __builtin_amdgcn_mfma_f32_16x16x32_f16(av0, bf, acc0[nt], 0, 0, 0);
          acc1[nt] = __builtin_amdgcn_mfma_f32_16x16x32_f16(av1, bf, acc1[nt], 0, 0, 0);
        }
      }
      __syncthreads();   // FREE: all waves finished reading slab (li,kt)
    }
    do_tile(acc0, R0,      false, cstF + 1536 + li * 256);
    do_tile(acc1, R0 + 16, false, cstF + 1536 + li * 256);
  }

  // ================= layer 8: out = z7 . (W8*gamma) + (beta@W8 + b8) =================
  {
    float wg8[16], be8 = 0.f;
    #pragma unroll
    for (int j = 0; j < 16; ++j) {
      int c = lm * 16 + j;
      float w = W8[c];
      wg8[j] = w * gamma[c];
      be8 = fmaf(w, beta[c], be8);
    }
    #pragma unroll
    for (int off = 1; off < 16; off <<= 1) be8 += __shfl_xor(be8, off, 64);
    float cb8 = be8 + b8[0];
    #pragma unroll
    for (int tile = 0; tile < 2; ++tile) {
      #pragma unroll
      for (int i = 0; i < 4; ++i) {
        int r = R0 + tile * 16 + lg * 4 + i;
        int s3 = ((r >> 1) & 7) << 3;
        f16x8 h0 = *(const f16x8*)&hbuf[r * 256 + ((lm * 16) ^ s3)];
        f16x8 h1 = *(const f16x8*)&hbuf[r * 256 + ((lm * 16 + 8) ^ s3)];
        float d = 0.f;
        #pragma unroll
        for (int j = 0; j < 8; ++j) d = fmaf((float)h0[j], wg8[j], d);
        #pragma unroll
        for (int j = 0; j < 8; ++j) d = fmaf((float)h1[j], wg8[8 + j], d);
        #pragma unroll
        for (int off = 1; off < 16; off <<= 1) d += __shfl_xor(d, off, 64);
        if (lm == 0) {
          long gr = rowbase + r;
          if (gr < N_ROWS) out[gr] = d + cb8;
        }
      }
    }
  }
}

extern "C" void kernel_launch(void* const* d_in, const int* in_sizes, int n_in,
                              void* d_out, int out_size, void* d_ws, size_t ws_size,
                              hipStream_t stream) {
  const float* x  = (const float*)d_in[0];
  const float* W1 = (const float*)d_in[1];
  const float* b1 = (const float*)d_in[2];
  const float* W2 = (const float*)d_in[3];
  const float* b2 = (const float*)d_in[4];
  const float* W3 = (const float*)d_in[5];
  const float* b3 = (const float*)d_in[6];
  const float* W4 = (const float*)d_in[7];
  const float* b4 = (const float*)d_in[8];
  const float* W5 = (const float*)d_in[9];
  const float* b5 = (const float*)d_in[10];
  const float* W6 = (const float*)d_in[11];
  const float* b6 = (const float*)d_in[12];
  const float* W7 = (const float*)d_in[13];
  const float* b7 = (const float*)d_in[14];
  const float* W8 = (const float*)d_in[15];
  const float* b8 = (const float*)d_in[16];
  const float* gm = (const float*)d_in[17];
  const float* bt = (const float*)d_in[18];
  f16* ws = (f16*)d_ws;
  float* out = (float*)d_out;

  prep_kernel<<<1606, 256, 0, stream>>>(W1, W2, W3, W4, W5, W6, W7,
                                        b2, b3, b4, b5, b6, b7, gm, bt, ws);

  int nblk = (N_ROWS + 127) / 128;   // 3907
  mlp_kernel<<<nblk, 256, 0, stream>>>(x, ws, b1, W8, b8, gm, bt, out);
}